// Round 1
// baseline (82.928 us; speedup 1.0000x reference)
//
#include <hip/hip_runtime.h>
#include <hip/hip_bf16.h>
#include <math.h>

// Problem: B=4, L=4096, D=1024, NB=4, TOPK=2
//   logits = x @ gate_w + gate_b          (B,L,4)
//   top-2 mask (keep logits >= 2nd-largest), softmax
//   out = sum_n w[n] * branches[:,:,n,:]  (B,L,D)
// Pure memory-bound fusion: 1 wave per row, no LDS, no barriers.

#define DDIM 1024
#define NBR 4

__global__ __launch_bounds__(256) void titan_fuse_kernel(
    const float* __restrict__ x,
    const float* __restrict__ branches,
    const float* __restrict__ gate_w,
    const float* __restrict__ gate_b,
    float* __restrict__ out,
    int nrows)
{
    const int lane = threadIdx.x & 63;
    const int wave = threadIdx.x >> 6;
    const int waves_per_block = blockDim.x >> 6;
    const int total_waves = gridDim.x * waves_per_block;
    const int wave_id = blockIdx.x * waves_per_block + wave;

    // Preload this lane's gate_w slice into registers (shared across rows).
    // Lane handles dims d = j*256 + lane*4 + k  (j=0..3, k=0..3).
    // gate_w is (D, NB) row-major: the 4 weights for dim d are a contiguous float4.
    float4 gw[4][4];
#pragma unroll
    for (int j = 0; j < 4; ++j)
#pragma unroll
        for (int k = 0; k < 4; ++k)
            gw[j][k] = *(const float4*)(gate_w + (size_t)((j * 256 + lane * 4 + k) * NBR));

    const float4 gb = *(const float4*)gate_b;

    for (int row = wave_id; row < nrows; row += total_waves) {
        const float* xr = x + (size_t)row * DDIM;

        // ---- gating matvec: 4 dots of length 1024 ----
        float acc0 = 0.f, acc1 = 0.f, acc2 = 0.f, acc3 = 0.f;
#pragma unroll
        for (int j = 0; j < 4; ++j) {
            const float4 xv = *(const float4*)(xr + j * 256 + lane * 4);
            const float xs[4] = {xv.x, xv.y, xv.z, xv.w};
#pragma unroll
            for (int k = 0; k < 4; ++k) {
                acc0 = fmaf(xs[k], gw[j][k].x, acc0);
                acc1 = fmaf(xs[k], gw[j][k].y, acc1);
                acc2 = fmaf(xs[k], gw[j][k].z, acc2);
                acc3 = fmaf(xs[k], gw[j][k].w, acc3);
            }
        }
        // wave-wide tree reduce (64 lanes) — all lanes end with full sums
#pragma unroll
        for (int off = 32; off >= 1; off >>= 1) {
            acc0 += __shfl_xor(acc0, off, 64);
            acc1 += __shfl_xor(acc1, off, 64);
            acc2 += __shfl_xor(acc2, off, 64);
            acc3 += __shfl_xor(acc3, off, 64);
        }

        float lg[NBR] = {acc0 + gb.x, acc1 + gb.y, acc2 + gb.z, acc3 + gb.w};

        // ---- top-2 threshold (reference: keep logits >= 2nd-largest) ----
        float m1 = -INFINITY, m2 = -INFINITY;
#pragma unroll
        for (int n = 0; n < NBR; ++n) {
            const float v = lg[n];
            if (v > m1) { m2 = m1; m1 = v; }
            else if (v > m2) { m2 = v; }
        }

        // ---- masked softmax over 4 ----
        float w[NBR];
        float s = 0.f;
#pragma unroll
        for (int n = 0; n < NBR; ++n) {
            const float e = (lg[n] >= m2) ? expf(lg[n] - m1) : 0.0f;
            w[n] = e;
            s += e;
        }
        const float inv = 1.0f / s;
#pragma unroll
        for (int n = 0; n < NBR; ++n) w[n] *= inv;

        // ---- fused = sum_n w[n] * branches[row, n, :] ----
        const float* br = branches + (size_t)row * (NBR * DDIM);
        float* outr = out + (size_t)row * DDIM;
#pragma unroll
        for (int j = 0; j < 4; ++j) {
            const int d = j * 256 + lane * 4;
            const float4 b0 = *(const float4*)(br + 0 * DDIM + d);
            const float4 b1 = *(const float4*)(br + 1 * DDIM + d);
            const float4 b2 = *(const float4*)(br + 2 * DDIM + d);
            const float4 b3 = *(const float4*)(br + 3 * DDIM + d);
            float4 o;
            o.x = w[0] * b0.x + w[1] * b1.x + w[2] * b2.x + w[3] * b3.x;
            o.y = w[0] * b0.y + w[1] * b1.y + w[2] * b2.y + w[3] * b3.y;
            o.z = w[0] * b0.z + w[1] * b1.z + w[2] * b2.z + w[3] * b3.z;
            o.w = w[0] * b0.w + w[1] * b1.w + w[2] * b2.w + w[3] * b3.w;
            *(float4*)(outr + d) = o;
        }
    }
}

extern "C" void kernel_launch(void* const* d_in, const int* in_sizes, int n_in,
                              void* d_out, int out_size, void* d_ws, size_t ws_size,
                              hipStream_t stream) {
    const float* x        = (const float*)d_in[0];
    const float* branches = (const float*)d_in[1];
    const float* gate_w   = (const float*)d_in[2];
    const float* gate_b   = (const float*)d_in[3];
    float* out = (float*)d_out;

    const int nrows = in_sizes[0] / DDIM;  // B*L = 16384

    const int block = 256;                  // 4 waves/block, 1 row per wave
    const int grid = 2048;                  // 8192 waves -> 2 rows each (grid-stride)
    hipLaunchKernelGGL(titan_fuse_kernel, dim3(grid), dim3(block), 0, stream,
                       x, branches, gate_w, gate_b, out, nrows);
}